// Round 2
// baseline (953.563 us; speedup 1.0000x reference)
//
#include <hip/hip_runtime.h>
#include <hip/hip_bf16.h>
#include <type_traits>

#define S_TOK 8192
#define HID 1024
#define INTERX 4096
#define NEXP 8
#define CAPX 1024

using f32x4 = __attribute__((ext_vector_type(4))) float;
using bf16x8 = __attribute__((ext_vector_type(8))) short;

__device__ __forceinline__ short f2bf(float f) {
    union { float f; unsigned u; } v; v.f = f;
    unsigned r = (v.u + 0x7FFFu + ((v.u >> 16) & 1u)) >> 16;
    return (short)r;
}

__device__ __forceinline__ float gelu_f(float x) {
    float u = 0.7978845608028654f * (x + 0.044715f * x * x * x);
    float e = __expf(2.0f * u);
    return 0.5f * x * (2.0f - 2.0f / (e + 1.0f));   // 0.5x(1+tanh(u)), overflow-safe
}

__device__ __forceinline__ void gl_lds16(const short* g, short* l) {
    __builtin_amdgcn_global_load_lds(
        (const __attribute__((address_space(1))) void*)g,
        (__attribute__((address_space(3))) void*)l, 16, 0, 0);
}

// ---------------------------------------------------------------------------
// Transpose-convert: src [b][K][N] fp32 -> dst [b][N][K] bf16. grid(N/64,K/64,b)
// 4x4 in-register micro-transpose -> LDS -> coalesced 128B row writes.
// ---------------------------------------------------------------------------
__global__ __launch_bounds__(256) void convtrans_kernel(
    const float* __restrict__ src, short* __restrict__ dst,
    int K, int N, long sSrc, long sDst)
{
    __shared__ __align__(16) short tile[64][72];
    long b = blockIdx.z;
    const float* s = src + b * sSrc;
    short* d = dst + b * sDst;
    int n0 = blockIdx.x * 64, k0 = blockIdx.y * 64;
    int t = threadIdx.x;
    int br = t >> 4, bc = t & 15;           // 4x4 block at (k0+br*4, n0+bc*4)
    const float* sp = s + (long)(k0 + br * 4) * N + n0 + bc * 4;
    float4 r0 = *(const float4*)(sp);
    float4 r1 = *(const float4*)(sp + N);
    float4 r2 = *(const float4*)(sp + 2 * (long)N);
    float4 r3 = *(const float4*)(sp + 3 * (long)N);
    short4 c0 = { f2bf(r0.x), f2bf(r1.x), f2bf(r2.x), f2bf(r3.x) };
    short4 c1 = { f2bf(r0.y), f2bf(r1.y), f2bf(r2.y), f2bf(r3.y) };
    short4 c2 = { f2bf(r0.z), f2bf(r1.z), f2bf(r2.z), f2bf(r3.z) };
    short4 c3 = { f2bf(r0.w), f2bf(r1.w), f2bf(r2.w), f2bf(r3.w) };
    *(short4*)&tile[bc * 4 + 0][br * 4] = c0;
    *(short4*)&tile[bc * 4 + 1][br * 4] = c1;
    *(short4*)&tile[bc * 4 + 2][br * 4] = c2;
    *(short4*)&tile[bc * 4 + 3][br * 4] = c3;
    __syncthreads();
    int n = t >> 2, kc = (t & 3) * 16;
    int4 o0 = *(const int4*)&tile[n][kc];
    int4 o1 = *(const int4*)&tile[n][kc + 8];
    short* dp = d + (long)(n0 + n) * K + k0 + kc;
    *(int4*)(dp) = o0;
    *(int4*)(dp + 8) = o1;
}

// ---------------------------------------------------------------------------
// LayerNorm + gate logits (fp64 accum) + coef logits, per token row.
// ---------------------------------------------------------------------------
__global__ __launch_bounds__(256) void ln_gate_kernel(
    const float* __restrict__ x, const float* __restrict__ nw, const float* __restrict__ nb,
    const float* __restrict__ wg, const float* __restrict__ rcf,
    short* __restrict__ attn_bf, int* __restrict__ eidx, float* __restrict__ gate,
    float* __restrict__ coef0, float* __restrict__ coef1)
{
    int s = blockIdx.x, tid = threadIdx.x;
    int lane = tid & 63, wave = tid >> 6;
    __shared__ float wred[4][2];
    __shared__ double gred[4][10];

    float4 xv = *(const float4*)(x + (size_t)s * HID + tid * 4);
    float sum = xv.x + xv.y + xv.z + xv.w;
    float sq  = xv.x*xv.x + xv.y*xv.y + xv.z*xv.z + xv.w*xv.w;
#pragma unroll
    for (int o = 32; o > 0; o >>= 1) {
        sum += __shfl_down(sum, o, 64);
        sq  += __shfl_down(sq, o, 64);
    }
    if (lane == 0) { wred[wave][0] = sum; wred[wave][1] = sq; }
    __syncthreads();
    float ts = wred[0][0] + wred[1][0] + wred[2][0] + wred[3][0];
    float tq = wred[0][1] + wred[1][1] + wred[2][1] + wred[3][1];
    float m  = ts * (1.0f / HID);
    float var = tq * (1.0f / HID) - m * m;
    float rs = rsqrtf(var + 1e-12f);

    float4 g4 = *(const float4*)(nw + tid * 4);
    float4 b4 = *(const float4*)(nb + tid * 4);
    float y[4];
    y[0] = (xv.x - m) * rs * g4.x + b4.x;
    y[1] = (xv.y - m) * rs * g4.y + b4.y;
    y[2] = (xv.z - m) * rs * g4.z + b4.z;
    y[3] = (xv.w - m) * rs * g4.w + b4.w;

    short4 yb = { f2bf(y[0]), f2bf(y[1]), f2bf(y[2]), f2bf(y[3]) };
    *(short4*)(attn_bf + (size_t)s * HID + tid * 4) = yb;

    double a[10];
#pragma unroll
    for (int q = 0; q < 10; q++) a[q] = 0.0;
#pragma unroll
    for (int j = 0; j < 4; j++) {
        int k = tid * 4 + j;
        float4 w0 = *(const float4*)(wg + k * 8);
        float4 w1 = *(const float4*)(wg + k * 8 + 4);
        double yj = (double)y[j];
        a[0] += yj * w0.x; a[1] += yj * w0.y; a[2] += yj * w0.z; a[3] += yj * w0.w;
        a[4] += yj * w1.x; a[5] += yj * w1.y; a[6] += yj * w1.z; a[7] += yj * w1.w;
        float2 rc = *(const float2*)(rcf + k * 2);
        a[8] += yj * rc.x; a[9] += yj * rc.y;
    }
#pragma unroll
    for (int o = 32; o > 0; o >>= 1)
#pragma unroll
        for (int q = 0; q < 10; q++) a[q] += __shfl_down(a[q], o, 64);
    if (lane == 0)
#pragma unroll
        for (int q = 0; q < 10; q++) gred[wave][q] = a[q];
    __syncthreads();
    if (tid == 0) {
        float l[8];
#pragma unroll
        for (int e = 0; e < 8; e++)
            l[e] = (float)(gred[0][e] + gred[1][e] + gred[2][e] + gred[3][e]);
        int bi = 0; float bv = l[0];
#pragma unroll
        for (int e = 1; e < 8; e++) if (l[e] > bv) { bv = l[e]; bi = e; }
        float den = 0.0f;
#pragma unroll
        for (int e = 0; e < 8; e++) den += expf(l[e] - bv);
        gate[s] = 1.0f / den;
        eidx[s] = bi;
        float r0 = (float)(gred[0][8] + gred[1][8] + gred[2][8] + gred[3][8]);
        float r1 = (float)(gred[0][9] + gred[1][9] + gred[2][9] + gred[3][9]);
        float mx = fmaxf(r0, r1);
        float e0 = expf(r0 - mx), e1 = expf(r1 - mx);
        float inv = 1.0f / (e0 + e1);
        coef0[s] = e0 * inv; coef1[s] = e1 * inv;
    }
}

// ---------------------------------------------------------------------------
// Capacity assignment — exclusive cumsum per expert in token order. 1 block.
// Also zeroes the 2KB zero-page (ws is re-poisoned 0xAA before every launch).
// ---------------------------------------------------------------------------
__global__ __launch_bounds__(256) void assign_kernel(
    const int* __restrict__ eidx, int* __restrict__ slot, int* __restrict__ map,
    short* __restrict__ zbuf)
{
    int tid = threadIdx.x;
    for (int i = tid; i < NEXP * CAPX; i += 256) map[i] = -1;
    for (int i = tid; i < 512; i += 256) ((int*)zbuf)[i] = 0;

    __shared__ int cnt[2][256][NEXP];
    int c[NEXP];
#pragma unroll
    for (int e = 0; e < NEXP; e++) c[e] = 0;
    int base = tid * 32;
    for (int t = 0; t < 32; t++) { int e = eidx[base + t]; c[e]++; }
#pragma unroll
    for (int e = 0; e < NEXP; e++) cnt[0][tid][e] = c[e];
    __syncthreads();

    int src = 0;
    for (int step = 1; step < 256; step <<= 1) {
        int dst = src ^ 1;
#pragma unroll
        for (int e = 0; e < NEXP; e++) {
            int v = cnt[src][tid][e];
            if (tid >= step) v += cnt[src][tid - step][e];
            cnt[dst][tid][e] = v;
        }
        __syncthreads();
        src = dst;
    }
    int off[NEXP];
#pragma unroll
    for (int e = 0; e < NEXP; e++) off[e] = (tid > 0) ? cnt[src][tid - 1][e] : 0;
    for (int t = 0; t < 32; t++) {
        int s = base + t;
        int e = eidx[s];
        int loc = off[e]++;
        if (loc < CAPX) { slot[s] = loc; map[e * CAPX + loc] = s; }
        else            { slot[s] = -1; }
    }
}

// ---------------------------------------------------------------------------
// m97-style GEMM: out[M,N] = epi(A[M,K]bf16 @ Wt[N,K]bf16 + bias[N])
// 128x128 tile, BK=64, global_load_lds width-16 staging, unpadded pitch-64 LDS.
// EPI: 0 = +bias f32 store, 1 = +bias gelu bf16 store, 2 = final MoE combine.
// GATHER: A rows gathered through map (empty slots -> zero page).
// ---------------------------------------------------------------------------
template<int EPI, int GATHER, typename OUT_T>
__global__ __launch_bounds__(256) void gemm_kernel(
    const short* __restrict__ A, const short* __restrict__ W,
    const float* __restrict__ bias, OUT_T* __restrict__ out,
    const int* __restrict__ map, const short* __restrict__ zbuf,
    const float* __restrict__ xp, const float* __restrict__ eoutp,
    const int* __restrict__ eidxp, const int* __restrict__ slotp,
    const float* __restrict__ gatep, const float* __restrict__ c0p,
    const float* __restrict__ c1p,
    int N, int K, long sA, long sW, long sB, long sO)
{
    __shared__ __align__(16) short a_lds[128 * 64];
    __shared__ __align__(16) short b_lds[128 * 64];

    long b = blockIdx.z;
    const short* Wb = W + b * sW;
    const float* biasb = bias + b * sB;
    OUT_T* outb = out + b * sO;

    int tid = threadIdx.x;
    int lane = tid & 63, wave = tid >> 6;
    int wm = wave & 1, wn = wave >> 1;
    int lm = lane & 15, lq = lane >> 4;
    int lr = lane >> 3, ch = lane & 7;      // staging: row-in-group, k-chunk

    const short* pA[4];
    const short* pB[4];
#pragma unroll
    for (int it = 0; it < 4; it++) {
        int g = wave * 4 + it;              // 0..15 row-groups of 8
        int row = g * 8 + lr;               // 0..127
        if (GATHER) {
            int s = map[b * CAPX + blockIdx.y * 128 + row];
            pA[it] = (s >= 0) ? (A + (long)s * HID) : zbuf;
        } else {
            pA[it] = A + b * sA + ((long)blockIdx.y * 128 + row) * K;
        }
        pB[it] = Wb + ((long)blockIdx.x * 128 + row) * K;
    }

    f32x4 acc[4][4];
#pragma unroll
    for (int i = 0; i < 4; i++)
#pragma unroll
        for (int j = 0; j < 4; j++) acc[i][j] = { 0.f, 0.f, 0.f, 0.f };

    for (int kb = 0; kb < K; kb += 64) {
#pragma unroll
        for (int it = 0; it < 4; it++) {
            int g = wave * 4 + it;
            gl_lds16(pA[it] + kb + ch * 8, a_lds + g * 512);
            gl_lds16(pB[it] + kb + ch * 8, b_lds + g * 512);
        }
        __syncthreads();
#pragma unroll
        for (int ks = 0; ks < 64; ks += 32) {
            bf16x8 af[4], bfr[4];
#pragma unroll
            for (int i = 0; i < 4; i++)
                af[i] = *(const bf16x8*)(a_lds + (wm * 64 + i * 16 + lm) * 64 + ks + lq * 8);
#pragma unroll
            for (int j = 0; j < 4; j++)
                bfr[j] = *(const bf16x8*)(b_lds + (wn * 64 + j * 16 + lm) * 64 + ks + lq * 8);
#pragma unroll
            for (int i = 0; i < 4; i++)
#pragma unroll
                for (int j = 0; j < 4; j++)
                    acc[i][j] = __builtin_amdgcn_mfma_f32_16x16x32_bf16(af[i], bfr[j], acc[i][j], 0, 0, 0);
        }
        __syncthreads();
    }

    // epilogue: C/D layout col=lane&15, row=(lane>>4)*4+r
    float bb[4];
#pragma unroll
    for (int j = 0; j < 4; j++)
        bb[j] = biasb[blockIdx.x * 128 + wn * 64 + j * 16 + lm];
#pragma unroll
    for (int i = 0; i < 4; i++) {
#pragma unroll
        for (int r = 0; r < 4; r++) {
            int row = blockIdx.y * 128 + wm * 64 + i * 16 + lq * 4 + r;
            if (EPI == 2) {
                int sl = slotp[row];
                float g2 = gatep[row] * c1p[row];
                float c0 = c0p[row];
                int e = eidxp[row];
#pragma unroll
                for (int j = 0; j < 4; j++) {
                    int col = blockIdx.x * 128 + wn * 64 + j * 16 + lm;
                    float v = acc[i][j][r] + bb[j];
                    float mo = 0.f;
                    if (sl >= 0) mo = eoutp[((long)e * CAPX + sl) * HID + col];
                    float res = xp[(long)row * HID + col];
                    ((float*)outb)[(long)row * N + col] = v * c0 + g2 * mo + res;
                }
            } else {
#pragma unroll
                for (int j = 0; j < 4; j++) {
                    int col = blockIdx.x * 128 + wn * 64 + j * 16 + lm;
                    float v = acc[i][j][r] + bb[j];
                    if (EPI == 1) outb[(long)row * N + col] = (OUT_T)f2bf(gelu_f(v));
                    else          outb[(long)row * N + col] = (OUT_T)v;
                }
            }
        }
    }
}

extern "C" void kernel_launch(void* const* d_in, const int* in_sizes, int n_in,
                              void* d_out, int out_size, void* d_ws, size_t ws_size,
                              hipStream_t stream) {
    const float* x           = (const float*)d_in[0];
    const float* attn_nw     = (const float*)d_in[1];
    const float* attn_nb     = (const float*)d_in[2];
    const float* wg          = (const float*)d_in[3];
    const float* inter_w     = (const float*)d_in[4];
    const float* inter_b     = (const float*)d_in[5];
    const float* output_w    = (const float*)d_in[6];
    const float* output_b    = (const float*)d_in[7];
    const float* res_inter_w = (const float*)d_in[8];
    const float* res_inter_b = (const float*)d_in[9];
    const float* res_output_w= (const float*)d_in[10];
    const float* res_output_b= (const float*)d_in[11];
    const float* res_coef    = (const float*)d_in[12];
    float* out = (float*)d_out;

    char* ws = (char*)d_ws;
    size_t off = 0;
    auto alloc = [&](size_t bytes) { void* p = ws + off; off += (bytes + 255) & ~(size_t)255; return p; };
    short* attn_bf  = (short*)alloc((size_t)S_TOK * HID * 2);           // 16 MiB
    short* hbuf     = (short*)alloc((size_t)NEXP * CAPX * INTERX * 2);  // 64 MiB (h then rh)
    float* eout     = (float*)alloc((size_t)NEXP * CAPX * HID * 4);     // 32 MiB
    short* inter_wt = (short*)alloc((size_t)NEXP * HID * INTERX * 2);   // 64 MiB
    short* output_wt= (short*)alloc((size_t)NEXP * INTERX * HID * 2);   // 64 MiB
    short* rinter_wt= (short*)alloc((size_t)HID * INTERX * 2);          // 8 MiB
    short* routput_wt=(short*)alloc((size_t)INTERX * HID * 2);          // 8 MiB
    int*   eidx     = (int*)alloc(S_TOK * 4);
    int*   slot     = (int*)alloc(S_TOK * 4);
    float* gate     = (float*)alloc(S_TOK * 4);
    float* c0       = (float*)alloc(S_TOK * 4);
    float* c1       = (float*)alloc(S_TOK * 4);
    int*   map      = (int*)alloc(NEXP * CAPX * 4);
    short* zbuf     = (short*)alloc(1024 * 2);

    // weight transpose-convert fp32 [K][N] -> bf16 [N][K]
    convtrans_kernel<<<dim3(INTERX/64, HID/64, NEXP), 256, 0, stream>>>(
        inter_w, inter_wt, HID, INTERX, (long)HID*INTERX, (long)HID*INTERX);
    convtrans_kernel<<<dim3(HID/64, INTERX/64, NEXP), 256, 0, stream>>>(
        output_w, output_wt, INTERX, HID, (long)INTERX*HID, (long)INTERX*HID);
    convtrans_kernel<<<dim3(INTERX/64, HID/64, 1), 256, 0, stream>>>(
        res_inter_w, rinter_wt, HID, INTERX, 0, 0);
    convtrans_kernel<<<dim3(HID/64, INTERX/64, 1), 256, 0, stream>>>(
        res_output_w, routput_wt, INTERX, HID, 0, 0);

    ln_gate_kernel<<<S_TOK, 256, 0, stream>>>(x, attn_nw, attn_nb, wg, res_coef,
                                              attn_bf, eidx, gate, c0, c1);
    assign_kernel<<<1, 256, 0, stream>>>(eidx, slot, map, zbuf);

    // expert GEMM1 (gather fused): [8][1024,1024]@[1024,4096] -> gelu -> h bf16
    gemm_kernel<1, 1, short><<<dim3(INTERX/128, CAPX/128, NEXP), 256, 0, stream>>>(
        attn_bf, inter_wt, inter_b, hbuf, map, zbuf,
        nullptr, nullptr, nullptr, nullptr, nullptr, nullptr, nullptr,
        INTERX, HID, 0, (long)HID*INTERX, INTERX, (long)CAPX*INTERX);
    // expert GEMM2: [8][1024,4096]@[4096,1024] -> eout f32
    gemm_kernel<0, 0, float><<<dim3(HID/128, CAPX/128, NEXP), 256, 0, stream>>>(
        hbuf, output_wt, output_b, eout, nullptr, nullptr,
        nullptr, nullptr, nullptr, nullptr, nullptr, nullptr, nullptr,
        HID, INTERX, (long)CAPX*INTERX, (long)INTERX*HID, HID, (long)CAPX*HID);
    // residual GEMM1: [8192,1024]@[1024,4096] -> gelu -> rh bf16 (reuse hbuf)
    gemm_kernel<1, 0, short><<<dim3(INTERX/128, S_TOK/128, 1), 256, 0, stream>>>(
        attn_bf, rinter_wt, res_inter_b, hbuf, nullptr, nullptr,
        nullptr, nullptr, nullptr, nullptr, nullptr, nullptr, nullptr,
        INTERX, HID, 0, 0, 0, 0);
    // residual GEMM2 + fused final combine -> d_out
    gemm_kernel<2, 0, float><<<dim3(HID/128, S_TOK/128, 1), 256, 0, stream>>>(
        hbuf, routput_wt, res_output_b, out, nullptr, nullptr,
        x, eout, eidx, slot, gate, c0, c1,
        HID, INTERX, 0, 0, 0, 0);

    (void)in_sizes; (void)n_in; (void)out_size; (void)ws_size;
}

// Round 3
// 872.943 us; speedup vs baseline: 1.0924x; 1.0924x over previous
//
#include <hip/hip_runtime.h>
#include <hip/hip_bf16.h>
#include <type_traits>

#define S_TOK 8192
#define HID 1024
#define INTERX 4096
#define NEXP 8
#define CAPX 1024
#define MTOT 16384   // merged M: 8192 expert slots + 8192 tokens

using f32x4 = __attribute__((ext_vector_type(4))) float;
using bf16x8 = __attribute__((ext_vector_type(8))) short;

__device__ __forceinline__ short f2bf(float f) {
    union { float f; unsigned u; } v; v.f = f;
    unsigned r = (v.u + 0x7FFFu + ((v.u >> 16) & 1u)) >> 16;
    return (short)r;
}
__device__ __forceinline__ float bflo(int p) {
    union { unsigned u; float f; } v; v.u = (unsigned)p << 16; return v.f;
}
__device__ __forceinline__ float bfhi(int p) {
    union { unsigned u; float f; } v; v.u = (unsigned)p & 0xffff0000u; return v.f;
}

__device__ __forceinline__ float gelu_f(float x) {
    float u = 0.7978845608028654f * (x + 0.044715f * x * x * x);
    float e = __expf(2.0f * u);
    return 0.5f * x * (2.0f - 2.0f / (e + 1.0f));
}

__device__ __forceinline__ void gl_lds16(const short* g, short* l) {
    __builtin_amdgcn_global_load_lds(
        (const __attribute__((address_space(1))) void*)g,
        (__attribute__((address_space(3))) void*)l, 16, 0, 0);
}

// ---------------------------------------------------------------------------
// Transpose-convert, 9-way batch: z<8 -> src_e + z*sSrc, z==8 -> src_r.
// src [K][N] fp32 -> dst[z] [N][K] bf16.
// ---------------------------------------------------------------------------
__global__ __launch_bounds__(256) void convtrans_kernel(
    const float* __restrict__ src_e, const float* __restrict__ src_r,
    short* __restrict__ dst, int K, int N, long sSrc, long sDst)
{
    __shared__ __align__(16) short tile[64][72];
    long z = blockIdx.z;
    const float* s = (z < 8) ? (src_e + z * sSrc) : src_r;
    short* d = dst + z * sDst;
    int n0 = blockIdx.x * 64, k0 = blockIdx.y * 64;
    int t = threadIdx.x;
    int br = t >> 4, bc = t & 15;
    const float* sp = s + (long)(k0 + br * 4) * N + n0 + bc * 4;
    float4 r0 = *(const float4*)(sp);
    float4 r1 = *(const float4*)(sp + N);
    float4 r2 = *(const float4*)(sp + 2 * (long)N);
    float4 r3 = *(const float4*)(sp + 3 * (long)N);
    short4 c0 = { f2bf(r0.x), f2bf(r1.x), f2bf(r2.x), f2bf(r3.x) };
    short4 c1 = { f2bf(r0.y), f2bf(r1.y), f2bf(r2.y), f2bf(r3.y) };
    short4 c2 = { f2bf(r0.z), f2bf(r1.z), f2bf(r2.z), f2bf(r3.z) };
    short4 c3 = { f2bf(r0.w), f2bf(r1.w), f2bf(r2.w), f2bf(r3.w) };
    *(short4*)&tile[bc * 4 + 0][br * 4] = c0;
    *(short4*)&tile[bc * 4 + 1][br * 4] = c1;
    *(short4*)&tile[bc * 4 + 2][br * 4] = c2;
    *(short4*)&tile[bc * 4 + 3][br * 4] = c3;
    __syncthreads();
    int n = t >> 2, kc = (t & 3) * 16;
    int4 o0 = *(const int4*)&tile[n][kc];
    int4 o1 = *(const int4*)&tile[n][kc + 8];
    short* dp = d + (long)(n0 + n) * K + k0 + kc;
    *(int4*)(dp) = o0;
    *(int4*)(dp + 8) = o1;
}

// ---------------------------------------------------------------------------
// LayerNorm + gate logits (fp64 accum) + coef logits, per token row.
// ---------------------------------------------------------------------------
__global__ __launch_bounds__(256) void ln_gate_kernel(
    const float* __restrict__ x, const float* __restrict__ nw, const float* __restrict__ nb,
    const float* __restrict__ wg, const float* __restrict__ rcf,
    short* __restrict__ attn_bf, int* __restrict__ eidx, float* __restrict__ gate,
    float* __restrict__ coef0, float* __restrict__ coef1)
{
    int s = blockIdx.x, tid = threadIdx.x;
    int lane = tid & 63, wave = tid >> 6;
    __shared__ float wred[4][2];
    __shared__ double gred[4][10];

    float4 xv = *(const float4*)(x + (size_t)s * HID + tid * 4);
    float sum = xv.x + xv.y + xv.z + xv.w;
    float sq  = xv.x*xv.x + xv.y*xv.y + xv.z*xv.z + xv.w*xv.w;
#pragma unroll
    for (int o = 32; o > 0; o >>= 1) {
        sum += __shfl_down(sum, o, 64);
        sq  += __shfl_down(sq, o, 64);
    }
    if (lane == 0) { wred[wave][0] = sum; wred[wave][1] = sq; }
    __syncthreads();
    float ts = wred[0][0] + wred[1][0] + wred[2][0] + wred[3][0];
    float tq = wred[0][1] + wred[1][1] + wred[2][1] + wred[3][1];
    float m  = ts * (1.0f / HID);
    float var = tq * (1.0f / HID) - m * m;
    float rs = rsqrtf(var + 1e-12f);

    float4 g4 = *(const float4*)(nw + tid * 4);
    float4 b4 = *(const float4*)(nb + tid * 4);
    float y[4];
    y[0] = (xv.x - m) * rs * g4.x + b4.x;
    y[1] = (xv.y - m) * rs * g4.y + b4.y;
    y[2] = (xv.z - m) * rs * g4.z + b4.z;
    y[3] = (xv.w - m) * rs * g4.w + b4.w;

    short4 yb = { f2bf(y[0]), f2bf(y[1]), f2bf(y[2]), f2bf(y[3]) };
    *(short4*)(attn_bf + (size_t)s * HID + tid * 4) = yb;

    double a[10];
#pragma unroll
    for (int q = 0; q < 10; q++) a[q] = 0.0;
#pragma unroll
    for (int j = 0; j < 4; j++) {
        int k = tid * 4 + j;
        float4 w0 = *(const float4*)(wg + k * 8);
        float4 w1 = *(const float4*)(wg + k * 8 + 4);
        double yj = (double)y[j];
        a[0] += yj * w0.x; a[1] += yj * w0.y; a[2] += yj * w0.z; a[3] += yj * w0.w;
        a[4] += yj * w1.x; a[5] += yj * w1.y; a[6] += yj * w1.z; a[7] += yj * w1.w;
        float2 rc = *(const float2*)(rcf + k * 2);
        a[8] += yj * rc.x; a[9] += yj * rc.y;
    }
#pragma unroll
    for (int o = 32; o > 0; o >>= 1)
#pragma unroll
        for (int q = 0; q < 10; q++) a[q] += __shfl_down(a[q], o, 64);
    if (lane == 0)
#pragma unroll
        for (int q = 0; q < 10; q++) gred[wave][q] = a[q];
    __syncthreads();
    if (tid == 0) {
        float l[8];
#pragma unroll
        for (int e = 0; e < 8; e++)
            l[e] = (float)(gred[0][e] + gred[1][e] + gred[2][e] + gred[3][e]);
        int bi = 0; float bv = l[0];
#pragma unroll
        for (int e = 1; e < 8; e++) if (l[e] > bv) { bv = l[e]; bi = e; }
        float den = 0.0f;
#pragma unroll
        for (int e = 0; e < 8; e++) den += expf(l[e] - bv);
        gate[s] = 1.0f / den;
        eidx[s] = bi;
        float r0 = (float)(gred[0][8] + gred[1][8] + gred[2][8] + gred[3][8]);
        float r1 = (float)(gred[0][9] + gred[1][9] + gred[2][9] + gred[3][9]);
        float mx = fmaxf(r0, r1);
        float e0 = expf(r0 - mx), e1 = expf(r1 - mx);
        float inv = 1.0f / (e0 + e1);
        coef0[s] = e0 * inv; coef1[s] = e1 * inv;
    }
}

// ---------------------------------------------------------------------------
// Capacity assignment (token-order exclusive cumsum per expert), 1 block.
// Fills map2: [0,8192) = expert-slot -> token (-1 empty), [8192,16384) = identity.
// ---------------------------------------------------------------------------
__global__ __launch_bounds__(256) void assign_kernel(
    const int* __restrict__ eidx, int* __restrict__ slot, int* __restrict__ map2,
    short* __restrict__ zbuf)
{
    int tid = threadIdx.x;
    for (int i = tid; i < NEXP * CAPX; i += 256) map2[i] = -1;
    for (int i = tid; i < S_TOK; i += 256) map2[NEXP * CAPX + i] = i;
    for (int i = tid; i < 512; i += 256) ((int*)zbuf)[i] = 0;

    __shared__ int cnt[2][256][NEXP];
    int c[NEXP];
#pragma unroll
    for (int e = 0; e < NEXP; e++) c[e] = 0;
    int base = tid * 32;
    for (int t = 0; t < 32; t++) { int e = eidx[base + t]; c[e]++; }
#pragma unroll
    for (int e = 0; e < NEXP; e++) cnt[0][tid][e] = c[e];
    __syncthreads();

    int src = 0;
    for (int step = 1; step < 256; step <<= 1) {
        int dst = src ^ 1;
#pragma unroll
        for (int e = 0; e < NEXP; e++) {
            int v = cnt[src][tid][e];
            if (tid >= step) v += cnt[src][tid - step][e];
            cnt[dst][tid][e] = v;
        }
        __syncthreads();
        src = dst;
    }
    int off[NEXP];
#pragma unroll
    for (int e = 0; e < NEXP; e++) off[e] = (tid > 0) ? cnt[src][tid - 1][e] : 0;
    for (int t = 0; t < 32; t++) {
        int s = base + t;
        int e = eidx[s];
        int loc = off[e]++;
        if (loc < CAPX) { slot[s] = loc; map2[e * CAPX + loc] = s; }
        else            { slot[s] = -1; }
    }
}

// ---------------------------------------------------------------------------
// Merged GEMM: out[16384,N] = epi(A @ W[e][N,K] + bias), e = min(by>>3, 8).
// 128x128 tile, BK=64, global_load_lds staging with XOR chunk swizzle
// (bank-conflict-free b128 frag reads), XCD swizzle for A-panel L2 locality.
// EPI: 0 = bias (+f2bf if OUT_T short), 1 = bias+gelu+bf16.
// GATHER: A rows via map2 (empty slots -> zero page).
// ---------------------------------------------------------------------------
template<int EPI, int GATHER, typename OUT_T>
__global__ __launch_bounds__(256) void gemm_kernel(
    const short* __restrict__ A, const short* __restrict__ W,
    const float* __restrict__ bias_e, const float* __restrict__ bias_r,
    OUT_T* __restrict__ out, const int* __restrict__ map2,
    const short* __restrict__ zbuf, int N, int K, long sW, long sB)
{
    __shared__ __align__(16) short a_lds[128 * 64];
    __shared__ __align__(16) short b_lds[128 * 64];

    // swizzle: all x-blocks of one A-row-panel on one XCD; gridDim.y must be 128
    int L = blockIdx.x + gridDim.x * blockIdx.y;
    int by = (L & 7) * 16 + ((L >> 3) & 15);
    int bx = L >> 7;

    long e = by >> 3; if (e > 8) e = 8;
    const short* Wb = W + e * sW;
    const float* biasb = (by < 64) ? (bias_e + e * sB) : bias_r;

    int tid = threadIdx.x;
    int lane = tid & 63, wave = tid >> 6;
    int wm = wave & 1, wn = wave >> 1;
    int lm = lane & 15, lq = lane >> 4;
    int lr = lane >> 3, ch = lane & 7;
    int chs = (ch ^ lr) * 8;               // XOR-swizzled global chunk offset

    const short* pA[4];
    const short* pB[4];
#pragma unroll
    for (int it = 0; it < 4; it++) {
        int g = wave * 4 + it;
        int row = g * 8 + lr;
        if (GATHER) {
            int s = map2[by * 128 + row];
            pA[it] = (s >= 0) ? (A + (long)s * K) : zbuf;
        } else {
            pA[it] = A + ((long)by * 128 + row) * K;
        }
        pB[it] = Wb + ((long)bx * 128 + row) * K;
    }

    f32x4 acc[4][4];
#pragma unroll
    for (int i = 0; i < 4; i++)
#pragma unroll
        for (int j = 0; j < 4; j++) acc[i][j] = { 0.f, 0.f, 0.f, 0.f };

    int poffA = ((lq ^ (lm & 7)) * 8);     // frag-read swizzled position (shorts)

    for (int kb = 0; kb < K; kb += 64) {
#pragma unroll
        for (int it = 0; it < 4; it++) {
            int g = wave * 4 + it;
            gl_lds16(pA[it] + kb + chs, a_lds + g * 512);
            gl_lds16(pB[it] + kb + chs, b_lds + g * 512);
        }
        __syncthreads();
#pragma unroll
        for (int ks = 0; ks < 64; ks += 32) {
            int po = poffA ^ ks;           // ks=32 flips chunk bit 2 (32 shorts)
            bf16x8 af[4], bfr[4];
#pragma unroll
            for (int i = 0; i < 4; i++)
                af[i] = *(const bf16x8*)(a_lds + (wm * 64 + i * 16 + lm) * 64 + po);
#pragma unroll
            for (int j = 0; j < 4; j++)
                bfr[j] = *(const bf16x8*)(b_lds + (wn * 64 + j * 16 + lm) * 64 + po);
#pragma unroll
            for (int i = 0; i < 4; i++)
#pragma unroll
                for (int j = 0; j < 4; j++)
                    acc[i][j] = __builtin_amdgcn_mfma_f32_16x16x32_bf16(af[i], bfr[j], acc[i][j], 0, 0, 0);
        }
        __syncthreads();
    }

    float bb[4];
#pragma unroll
    for (int j = 0; j < 4; j++)
        bb[j] = biasb[bx * 128 + wn * 64 + j * 16 + lm];
#pragma unroll
    for (int i = 0; i < 4; i++) {
#pragma unroll
        for (int r = 0; r < 4; r++) {
            int row = by * 128 + wm * 64 + i * 16 + lq * 4 + r;
#pragma unroll
            for (int j = 0; j < 4; j++) {
                int col = bx * 128 + wn * 64 + j * 16 + lm;
                float v = acc[i][j][r] + bb[j];
                if (EPI == 1) v = gelu_f(v);
                if constexpr (std::is_same_v<OUT_T, short>)
                    out[(long)row * N + col] = f2bf(v);
                else
                    out[(long)row * N + col] = v;
            }
        }
    }
}

// ---------------------------------------------------------------------------
// Final combine: out = res_mlp*c0 + gate*expert_out*c1 + residual  (eout bf16)
// ---------------------------------------------------------------------------
__global__ __launch_bounds__(256) void final_kernel(
    const float* __restrict__ x, const short* __restrict__ eout2,
    const int* __restrict__ eidx, const int* __restrict__ slot,
    const float* __restrict__ gate, const float* __restrict__ coef0,
    const float* __restrict__ coef1, float* __restrict__ out)
{
    int s = blockIdx.x, tid = threadIdx.x;
    float c0 = coef0[s], g = gate[s] * coef1[s];
    int sl = slot[s], e = eidx[s];
    float4 xv = *(const float4*)(x + (size_t)s * HID + tid * 4);
    int2 rm = *(const int2*)(eout2 + ((size_t)(NEXP * CAPX + s)) * HID + tid * 4);
    int2 mo = { 0, 0 };
    if (sl >= 0) mo = *(const int2*)(eout2 + ((size_t)(e * CAPX + sl)) * HID + tid * 4);
    float4 o;
    o.x = bflo(rm.x) * c0 + g * bflo(mo.x) + xv.x;
    o.y = bfhi(rm.x) * c0 + g * bfhi(mo.x) + xv.y;
    o.z = bflo(rm.y) * c0 + g * bflo(mo.y) + xv.z;
    o.w = bfhi(rm.y) * c0 + g * bfhi(mo.y) + xv.w;
    *(float4*)(out + (size_t)s * HID + tid * 4) = o;
}

extern "C" void kernel_launch(void* const* d_in, const int* in_sizes, int n_in,
                              void* d_out, int out_size, void* d_ws, size_t ws_size,
                              hipStream_t stream) {
    const float* x           = (const float*)d_in[0];
    const float* attn_nw     = (const float*)d_in[1];
    const float* attn_nb     = (const float*)d_in[2];
    const float* wg          = (const float*)d_in[3];
    const float* inter_w     = (const float*)d_in[4];
    const float* inter_b     = (const float*)d_in[5];
    const float* output_w    = (const float*)d_in[6];
    const float* output_b    = (const float*)d_in[7];
    const float* res_inter_w = (const float*)d_in[8];
    const float* res_inter_b = (const float*)d_in[9];
    const float* res_output_w= (const float*)d_in[10];
    const float* res_output_b= (const float*)d_in[11];
    const float* res_coef    = (const float*)d_in[12];
    float* out = (float*)d_out;

    char* ws = (char*)d_ws;
    size_t off = 0;
    auto alloc = [&](size_t bytes) { void* p = ws + off; off += (bytes + 255) & ~(size_t)255; return p; };
    // region1: attn_bf (16 MiB, dies after GEMM1) then eout2 (32 MiB, GEMM2 out)
    char* region1 = (char*)alloc((size_t)MTOT * HID * 2);               // 32 MiB
    // wreg: w1t [9][4096][1024] (dies after GEMM1) then w2t [9][1024][4096]
    short* wreg   = (short*)alloc((size_t)9 * HID * INTERX * 2);        // 72 MiB
    short* hbuf2  = (short*)alloc((size_t)MTOT * INTERX * 2);           // 128 MiB
    int*   eidx   = (int*)alloc(S_TOK * 4);
    int*   slot   = (int*)alloc(S_TOK * 4);
    float* gate   = (float*)alloc(S_TOK * 4);
    float* c0     = (float*)alloc(S_TOK * 4);
    float* c1     = (float*)alloc(S_TOK * 4);
    int*   map2   = (int*)alloc(MTOT * 4);
    short* zbuf   = (short*)alloc(1024 * 2);

    short* attn_bf = (short*)region1;
    short* eout2   = (short*)region1;
    short* w1t = wreg;
    short* w2t = wreg;

    // weights for GEMM1: [9][N=4096][K=1024] bf16
    convtrans_kernel<<<dim3(INTERX/64, HID/64, 9), 256, 0, stream>>>(
        inter_w, res_inter_w, w1t, HID, INTERX, (long)HID*INTERX, (long)HID*INTERX);

    ln_gate_kernel<<<S_TOK, 256, 0, stream>>>(x, attn_nw, attn_nb, wg, res_coef,
                                              attn_bf, eidx, gate, c0, c1);
    assign_kernel<<<1, 256, 0, stream>>>(eidx, slot, map2, zbuf);

    // merged GEMM1: [16384,1024]@[9-sel][1024->4096] -> gelu -> hbuf2 bf16
    gemm_kernel<1, 1, short><<<dim3(INTERX/128, 128), 256, 0, stream>>>(
        attn_bf, w1t, inter_b, res_inter_b, hbuf2, map2, zbuf,
        INTERX, HID, (long)HID*INTERX, INTERX);

    // weights for GEMM2: [9][N=1024][K=4096] bf16 (overwrites dead w1t)
    convtrans_kernel<<<dim3(HID/64, INTERX/64, 9), 256, 0, stream>>>(
        output_w, res_output_w, w2t, INTERX, HID, (long)INTERX*HID, (long)INTERX*HID);

    // merged GEMM2: [16384,4096]@[9-sel][4096->1024] -> eout2 bf16 (over dead attn_bf)
    gemm_kernel<0, 0, short><<<dim3(HID/128, 128), 256, 0, stream>>>(
        hbuf2, w2t, output_b, res_output_b, eout2, nullptr, nullptr,
        HID, INTERX, (long)INTERX*HID, HID);

    final_kernel<<<S_TOK, 256, 0, stream>>>(x, eout2, eidx, slot, gate, c0, c1, out);

    (void)in_sizes; (void)n_in; (void)out_size; (void)ws_size;
}

// Round 4
// 732.813 us; speedup vs baseline: 1.3012x; 1.1912x over previous
//
#include <hip/hip_runtime.h>
#include <hip/hip_bf16.h>
#include <type_traits>

#define S_TOK 8192
#define HID 1024
#define INTERX 4096
#define NEXP 8
#define CAPX 1024
#define MTOT 16384   // merged M: 8192 expert slots + 8192 tokens

using f32x4 = __attribute__((ext_vector_type(4))) float;
using bf16x8 = __attribute__((ext_vector_type(8))) short;

__device__ __forceinline__ short f2bf(float f) {
    union { float f; unsigned u; } v; v.f = f;
    unsigned r = (v.u + 0x7FFFu + ((v.u >> 16) & 1u)) >> 16;
    return (short)r;
}
__device__ __forceinline__ float bflo(int p) {
    union { unsigned u; float f; } v; v.u = (unsigned)p << 16; return v.f;
}
__device__ __forceinline__ float bfhi(int p) {
    union { unsigned u; float f; } v; v.u = (unsigned)p & 0xffff0000u; return v.f;
}

// gelu(x) = x / (1 + e^{-2u}), u = 0.79788456(x + 0.044715x^3)
__device__ __forceinline__ float gelu_f(float x) {
    float x2 = x * x;
    float t = __expf(x * fmaf(x2, -0.07135677f, -1.5957691f));
    return x * __builtin_amdgcn_rcpf(1.0f + t);
}

__device__ __forceinline__ void gl_lds16(const short* g, short* l) {
    __builtin_amdgcn_global_load_lds(
        (const __attribute__((address_space(1))) void*)g,
        (__attribute__((address_space(3))) void*)l, 16, 0, 0);
}

// ---------------------------------------------------------------------------
// Transpose-convert, 9-way batch: z<8 -> src_e + z*sSrc, z==8 -> src_r.
// src [K][N] fp32 -> dst[z] [N][K] bf16. PERM: apply pi within 64-k groups,
// pi(kl) = (kl&15)*4 + (kl>>4)  (must match GEMM1's packed-store layout).
// ---------------------------------------------------------------------------
template<int PERM>
__global__ __launch_bounds__(256) void convtrans_kernel(
    const float* __restrict__ src_e, const float* __restrict__ src_r,
    short* __restrict__ dst, int K, int N, long sSrc, long sDst)
{
    __shared__ __align__(16) short tile[64][72];
    long z = blockIdx.z;
    const float* s = (z < 8) ? (src_e + z * sSrc) : src_r;
    short* d = dst + z * sDst;
    int n0 = blockIdx.x * 64, k0 = blockIdx.y * 64;
    int t = threadIdx.x;
    int br = t >> 4, bc = t & 15;
    const float* sp = s + (long)(k0 + br * 4) * N + n0 + bc * 4;
    float4 r0 = *(const float4*)(sp);
    float4 r1 = *(const float4*)(sp + N);
    float4 r2 = *(const float4*)(sp + 2 * (long)N);
    float4 r3 = *(const float4*)(sp + 3 * (long)N);
    if (PERM) {
        float rr[4][4] = { {r0.x,r0.y,r0.z,r0.w}, {r1.x,r1.y,r1.z,r1.w},
                           {r2.x,r2.y,r2.z,r2.w}, {r3.x,r3.y,r3.z,r3.w} };
#pragma unroll
        for (int j = 0; j < 4; j++) {
            int kl = br * 4 + j;
            int kp = (kl & 15) * 4 + (kl >> 4);
#pragma unroll
            for (int q = 0; q < 4; q++)
                tile[bc * 4 + q][kp] = f2bf(rr[j][q]);
        }
    } else {
        short4 c0 = { f2bf(r0.x), f2bf(r1.x), f2bf(r2.x), f2bf(r3.x) };
        short4 c1 = { f2bf(r0.y), f2bf(r1.y), f2bf(r2.y), f2bf(r3.y) };
        short4 c2 = { f2bf(r0.z), f2bf(r1.z), f2bf(r2.z), f2bf(r3.z) };
        short4 c3 = { f2bf(r0.w), f2bf(r1.w), f2bf(r2.w), f2bf(r3.w) };
        *(short4*)&tile[bc * 4 + 0][br * 4] = c0;
        *(short4*)&tile[bc * 4 + 1][br * 4] = c1;
        *(short4*)&tile[bc * 4 + 2][br * 4] = c2;
        *(short4*)&tile[bc * 4 + 3][br * 4] = c3;
    }
    __syncthreads();
    int n = t >> 2, kc = (t & 3) * 16;
    int4 o0 = *(const int4*)&tile[n][kc];
    int4 o1 = *(const int4*)&tile[n][kc + 8];
    short* dp = d + (long)(n0 + n) * K + k0 + kc;
    *(int4*)(dp) = o0;
    *(int4*)(dp + 8) = o1;
}

// ---------------------------------------------------------------------------
// LayerNorm + gate logits (fp64 accum) + coef logits, per token row.
// Also initializes map2 (-1 / identity) and zbuf (block 0).
// ---------------------------------------------------------------------------
__global__ __launch_bounds__(256) void ln_gate_kernel(
    const float* __restrict__ x, const float* __restrict__ nw, const float* __restrict__ nb,
    const float* __restrict__ wg, const float* __restrict__ rcf,
    short* __restrict__ attn_bf, int* __restrict__ eidx, float* __restrict__ gate,
    float* __restrict__ coef0, float* __restrict__ coef1,
    int* __restrict__ map2, int* __restrict__ zbufi)
{
    int s = blockIdx.x, tid = threadIdx.x;
    int lane = tid & 63, wave = tid >> 6;
    __shared__ float wred[4][2];
    __shared__ double gred[4][10];

    if (tid == 0) {
        map2[s] = -1;                 // expert-slot region default
        map2[NEXP * CAPX + s] = s;    // residual region identity
    }
    if (s == 0) ((int2*)zbufi)[tid] = int2{0, 0};

    float4 xv = *(const float4*)(x + (size_t)s * HID + tid * 4);
    float sum = xv.x + xv.y + xv.z + xv.w;
    float sq  = xv.x*xv.x + xv.y*xv.y + xv.z*xv.z + xv.w*xv.w;
#pragma unroll
    for (int o = 32; o > 0; o >>= 1) {
        sum += __shfl_down(sum, o, 64);
        sq  += __shfl_down(sq, o, 64);
    }
    if (lane == 0) { wred[wave][0] = sum; wred[wave][1] = sq; }
    __syncthreads();
    float ts = wred[0][0] + wred[1][0] + wred[2][0] + wred[3][0];
    float tq = wred[0][1] + wred[1][1] + wred[2][1] + wred[3][1];
    float m  = ts * (1.0f / HID);
    float var = tq * (1.0f / HID) - m * m;
    float rs = rsqrtf(var + 1e-12f);

    float4 g4 = *(const float4*)(nw + tid * 4);
    float4 b4 = *(const float4*)(nb + tid * 4);
    float y[4];
    y[0] = (xv.x - m) * rs * g4.x + b4.x;
    y[1] = (xv.y - m) * rs * g4.y + b4.y;
    y[2] = (xv.z - m) * rs * g4.z + b4.z;
    y[3] = (xv.w - m) * rs * g4.w + b4.w;

    short4 yb = { f2bf(y[0]), f2bf(y[1]), f2bf(y[2]), f2bf(y[3]) };
    *(short4*)(attn_bf + (size_t)s * HID + tid * 4) = yb;

    double a[10];
#pragma unroll
    for (int q = 0; q < 10; q++) a[q] = 0.0;
#pragma unroll
    for (int j = 0; j < 4; j++) {
        int k = tid * 4 + j;
        float4 w0 = *(const float4*)(wg + k * 8);
        float4 w1 = *(const float4*)(wg + k * 8 + 4);
        double yj = (double)y[j];
        a[0] += yj * w0.x; a[1] += yj * w0.y; a[2] += yj * w0.z; a[3] += yj * w0.w;
        a[4] += yj * w1.x; a[5] += yj * w1.y; a[6] += yj * w1.z; a[7] += yj * w1.w;
        float2 rc = *(const float2*)(rcf + k * 2);
        a[8] += yj * rc.x; a[9] += yj * rc.y;
    }
#pragma unroll
    for (int o = 32; o > 0; o >>= 1)
#pragma unroll
        for (int q = 0; q < 10; q++) a[q] += __shfl_down(a[q], o, 64);
    if (lane == 0)
#pragma unroll
        for (int q = 0; q < 10; q++) gred[wave][q] = a[q];
    __syncthreads();
    if (tid == 0) {
        float l[8];
#pragma unroll
        for (int e = 0; e < 8; e++)
            l[e] = (float)(gred[0][e] + gred[1][e] + gred[2][e] + gred[3][e]);
        int bi = 0; float bv = l[0];
#pragma unroll
        for (int e = 1; e < 8; e++) if (l[e] > bv) { bv = l[e]; bi = e; }
        float den = 0.0f;
#pragma unroll
        for (int e = 0; e < 8; e++) den += expf(l[e] - bv);
        gate[s] = 1.0f / den;
        eidx[s] = bi;
        float r0 = (float)(gred[0][8] + gred[1][8] + gred[2][8] + gred[3][8]);
        float r1 = (float)(gred[0][9] + gred[1][9] + gred[2][9] + gred[3][9]);
        float mx = fmaxf(r0, r1);
        float e0 = expf(r0 - mx), e1 = expf(r1 - mx);
        float inv = 1.0f / (e0 + e1);
        coef0[s] = e0 * inv; coef1[s] = e1 * inv;
    }
}

// ---------------------------------------------------------------------------
// Capacity assignment (token-order exclusive cumsum per expert), 1 block.
// ---------------------------------------------------------------------------
__global__ __launch_bounds__(256) void assign_kernel(
    const int* __restrict__ eidx, int* __restrict__ slot, int* __restrict__ map2)
{
    int tid = threadIdx.x;
    __shared__ int cnt[2][256][NEXP];
    int c[NEXP];
#pragma unroll
    for (int e = 0; e < NEXP; e++) c[e] = 0;
    int base = tid * 32;
    for (int t = 0; t < 32; t++) { int e = eidx[base + t]; c[e]++; }
#pragma unroll
    for (int e = 0; e < NEXP; e++) cnt[0][tid][e] = c[e];
    __syncthreads();

    int src = 0;
    for (int step = 1; step < 256; step <<= 1) {
        int dst = src ^ 1;
#pragma unroll
        for (int e = 0; e < NEXP; e++) {
            int v = cnt[src][tid][e];
            if (tid >= step) v += cnt[src][tid - step][e];
            cnt[dst][tid][e] = v;
        }
        __syncthreads();
        src = dst;
    }
    int off[NEXP];
#pragma unroll
    for (int e = 0; e < NEXP; e++) off[e] = (tid > 0) ? cnt[src][tid - 1][e] : 0;
    for (int t = 0; t < 32; t++) {
        int s = base + t;
        int e = eidx[s];
        int loc = off[e]++;
        if (loc < CAPX) { slot[s] = loc; map2[e * CAPX + loc] = s; }
        else            { slot[s] = -1; }
    }
}

// ---------------------------------------------------------------------------
// Merged GEMM, 128(M)x256(N) block, 4 waves of 64x128, BK=64.
// global_load_lds staging + XOR chunk swizzle (conflict-free b128 frag reads).
// EPI 1: gelu + pi-packed int2 bf16 stores (k-dim permuted within 64-groups,
//        matched by convtrans<1> on the next GEMM's weights).
// EPI 0: bias + scalar bf16 stores, plain layout.
// ---------------------------------------------------------------------------
template<int EPI, int GATHER>
__global__ __launch_bounds__(256, 2) void gemm_kernel(
    const short* __restrict__ A, const short* __restrict__ W,
    const float* __restrict__ bias_e, const float* __restrict__ bias_r,
    short* __restrict__ out, const int* __restrict__ map2,
    const short* __restrict__ zbuf, int N, int K, long sW, long sB)
{
    __shared__ __align__(16) short a_lds[128 * 64];
    __shared__ __align__(16) short b_lds[256 * 64];

    // swizzle: 16 consecutive by-panels per XCD (L%8), bx outer within XCD
    int L = blockIdx.x + gridDim.x * blockIdx.y;
    int by = (L & 7) * 16 + ((L >> 3) & 15);
    int bx = L >> 7;

    long e = by >> 3; if (e > 8) e = 8;
    const short* Wb = W + e * sW;
    const float* biasb = (by < 64) ? (bias_e + e * sB) : bias_r;

    int tid = threadIdx.x;
    int lane = tid & 63, wave = tid >> 6;
    int wm = wave & 1, wn = wave >> 1;
    int lm = lane & 15, lq = lane >> 4;
    int lr = lane >> 3, ch = lane & 7;
    int chs = (ch ^ lr) * 8;               // XOR-swizzled global chunk offset

    const short* pA[4];
    const short* pB[8];
#pragma unroll
    for (int it = 0; it < 4; it++) {
        int row = (wave * 4 + it) * 8 + lr;            // 0..127
        if (GATHER) {
            int s = map2[by * 128 + row];
            pA[it] = (s >= 0) ? (A + (long)s * K) : zbuf;
        } else {
            pA[it] = A + ((long)by * 128 + row) * K;
        }
    }
#pragma unroll
    for (int it = 0; it < 8; it++) {
        int row = (wave * 8 + it) * 8 + lr;            // 0..255
        pB[it] = Wb + ((long)bx * 256 + row) * K;
    }

    f32x4 acc[4][8];
#pragma unroll
    for (int i = 0; i < 4; i++)
#pragma unroll
        for (int j = 0; j < 8; j++) acc[i][j] = { 0.f, 0.f, 0.f, 0.f };

    for (int kb = 0; kb < K; kb += 64) {
#pragma unroll
        for (int it = 0; it < 4; it++)
            gl_lds16(pA[it] + kb + chs, a_lds + (wave * 4 + it) * 512);
#pragma unroll
        for (int it = 0; it < 8; it++)
            gl_lds16(pB[it] + kb + chs, b_lds + (wave * 8 + it) * 512);
        __syncthreads();
#pragma unroll
        for (int ks = 0; ks < 64; ks += 32) {
            int po = ((lq ^ (lm & 7)) * 8) ^ ks;
            bf16x8 af[4], bfr[8];
#pragma unroll
            for (int i = 0; i < 4; i++)
                af[i] = *(const bf16x8*)(a_lds + (wm * 64 + i * 16 + lm) * 64 + po);
#pragma unroll
            for (int j = 0; j < 8; j++)
                bfr[j] = *(const bf16x8*)(b_lds + (wn * 128 + j * 16 + lm) * 64 + po);
#pragma unroll
            for (int i = 0; i < 4; i++)
#pragma unroll
                for (int j = 0; j < 8; j++)
                    acc[i][j] = __builtin_amdgcn_mfma_f32_16x16x32_bf16(af[i], bfr[j], acc[i][j], 0, 0, 0);
        }
        __syncthreads();
    }

    // epilogue: C/D layout col=lane&15 (lm), row=lq*4+r
    float bb[8];
#pragma unroll
    for (int j = 0; j < 8; j++)
        bb[j] = biasb[bx * 256 + wn * 128 + j * 16 + lm];

#pragma unroll
    for (int i = 0; i < 4; i++) {
#pragma unroll
        for (int r = 0; r < 4; r++) {
            long row = (long)by * 128 + wm * 64 + i * 16 + lq * 4 + r;
            if (EPI == 1) {
                short* rp = out + row * N + bx * 256 + wn * 128;
#pragma unroll
                for (int h = 0; h < 2; h++) {
                    int b0 = f2bf(gelu_f(acc[i][h*4+0][r] + bb[h*4+0]));
                    int b1 = f2bf(gelu_f(acc[i][h*4+1][r] + bb[h*4+1]));
                    int b2 = f2bf(gelu_f(acc[i][h*4+2][r] + bb[h*4+2]));
                    int b3 = f2bf(gelu_f(acc[i][h*4+3][r] + bb[h*4+3]));
                    int2 pk;
                    pk.x = (b0 & 0xFFFF) | (b1 << 16);
                    pk.y = (b2 & 0xFFFF) | (b3 << 16);
                    *(int2*)(rp + h * 64 + lm * 4) = pk;   // pi(c)=(c&15)*4+(c>>4)
                }
            } else {
#pragma unroll
                for (int j = 0; j < 8; j++) {
                    int col = bx * 256 + wn * 128 + j * 16 + lm;
                    out[row * N + col] = f2bf(acc[i][j][r] + bb[j]);
                }
            }
        }
    }
}

// ---------------------------------------------------------------------------
// Final combine: out = res_mlp*c0 + gate*expert_out*c1 + residual  (eout bf16)
// ---------------------------------------------------------------------------
__global__ __launch_bounds__(256) void final_kernel(
    const float* __restrict__ x, const short* __restrict__ eout2,
    const int* __restrict__ eidx, const int* __restrict__ slot,
    const float* __restrict__ gate, const float* __restrict__ coef0,
    const float* __restrict__ coef1, float* __restrict__ out)
{
    int s = blockIdx.x, tid = threadIdx.x;
    float c0 = coef0[s], g = gate[s] * coef1[s];
    int sl = slot[s], e = eidx[s];
    float4 xv = *(const float4*)(x + (size_t)s * HID + tid * 4);
    int2 rm = *(const int2*)(eout2 + ((size_t)(NEXP * CAPX + s)) * HID + tid * 4);
    int2 mo = { 0, 0 };
    if (sl >= 0) mo = *(const int2*)(eout2 + ((size_t)(e * CAPX + sl)) * HID + tid * 4);
    float4 o;
    o.x = bflo(rm.x) * c0 + g * bflo(mo.x) + xv.x;
    o.y = bfhi(rm.x) * c0 + g * bfhi(mo.x) + xv.y;
    o.z = bflo(rm.y) * c0 + g * bflo(mo.y) + xv.z;
    o.w = bfhi(rm.y) * c0 + g * bfhi(mo.y) + xv.w;
    *(float4*)(out + (size_t)s * HID + tid * 4) = o;
}

extern "C" void kernel_launch(void* const* d_in, const int* in_sizes, int n_in,
                              void* d_out, int out_size, void* d_ws, size_t ws_size,
                              hipStream_t stream) {
    const float* x           = (const float*)d_in[0];
    const float* attn_nw     = (const float*)d_in[1];
    const float* attn_nb     = (const float*)d_in[2];
    const float* wg          = (const float*)d_in[3];
    const float* inter_w     = (const float*)d_in[4];
    const float* inter_b     = (const float*)d_in[5];
    const float* output_w    = (const float*)d_in[6];
    const float* output_b    = (const float*)d_in[7];
    const float* res_inter_w = (const float*)d_in[8];
    const float* res_inter_b = (const float*)d_in[9];
    const float* res_output_w= (const float*)d_in[10];
    const float* res_output_b= (const float*)d_in[11];
    const float* res_coef    = (const float*)d_in[12];
    float* out = (float*)d_out;

    char* ws = (char*)d_ws;
    size_t off = 0;
    auto alloc = [&](size_t bytes) { void* p = ws + off; off += (bytes + 255) & ~(size_t)255; return p; };
    // region1: attn_bf (16 MiB, dies after GEMM1) then eout2 (32 MiB, GEMM2 out)
    char* region1 = (char*)alloc((size_t)MTOT * HID * 2);               // 32 MiB
    // wreg: w1t [9][4096][1024] (dies after GEMM1) then w2t [9][1024][4096]
    short* wreg   = (short*)alloc((size_t)9 * HID * INTERX * 2);        // 72 MiB
    short* hbuf2  = (short*)alloc((size_t)MTOT * INTERX * 2);           // 128 MiB
    int*   eidx   = (int*)alloc(S_TOK * 4);
    int*   slot   = (int*)alloc(S_TOK * 4);
    float* gate   = (float*)alloc(S_TOK * 4);
    float* c0     = (float*)alloc(S_TOK * 4);
    float* c1     = (float*)alloc(S_TOK * 4);
    int*   map2   = (int*)alloc(MTOT * 4);
    short* zbuf   = (short*)alloc(1024 * 2);

    short* attn_bf = (short*)region1;
    short* eout2   = (short*)region1;
    short* w1t = wreg;
    short* w2t = wreg;

    // weights for GEMM1: [9][N=4096][K=1024] bf16, plain k order
    convtrans_kernel<0><<<dim3(INTERX/64, HID/64, 9), 256, 0, stream>>>(
        inter_w, res_inter_w, w1t, HID, INTERX, (long)HID*INTERX, (long)HID*INTERX);

    ln_gate_kernel<<<S_TOK, 256, 0, stream>>>(x, attn_nw, attn_nb, wg, res_coef,
                                              attn_bf, eidx, gate, c0, c1,
                                              map2, (int*)zbuf);
    assign_kernel<<<1, 256, 0, stream>>>(eidx, slot, map2);

    // merged GEMM1: [16384,1024]@[9-sel][1024->4096] -> gelu -> hbuf2 (pi-packed)
    gemm_kernel<1, 1><<<dim3(INTERX/256, 128), 256, 0, stream>>>(
        attn_bf, w1t, inter_b, res_inter_b, hbuf2, map2, zbuf,
        INTERX, HID, (long)HID*INTERX, INTERX);

    // weights for GEMM2: [9][N=1024][K=4096] bf16, pi-permuted K (matches hbuf2)
    convtrans_kernel<1><<<dim3(HID/64, INTERX/64, 9), 256, 0, stream>>>(
        output_w, res_output_w, w2t, INTERX, HID, (long)INTERX*HID, (long)INTERX*HID);

    // merged GEMM2: [16384,4096]@[9-sel][4096->1024] -> eout2 bf16 (plain layout)
    gemm_kernel<0, 0><<<dim3(HID/256, 128), 256, 0, stream>>>(
        hbuf2, w2t, output_b, res_output_b, eout2, nullptr, zbuf,
        HID, INTERX, (long)INTERX*HID, HID);

    final_kernel<<<S_TOK, 256, 0, stream>>>(x, eout2, eidx, slot, gate, c0, c1, out);

    (void)in_sizes; (void)n_in; (void)out_size; (void)ws_size;
}